// Round 7
// baseline (355.011 us; speedup 1.0000x reference)
//
#include <hip/hip_runtime.h>
#include <hip/hip_bf16.h>

// MQA fused pipeline, bf16 MFMA (32x32x16), fp32 accumulate.
// B=2, L=2048, D_MODEL=2048, H=16, HD=128.
// HARNESS DTYPES (established r1-r3): inputs fp32, OUTPUT fp32
// (threshold bf16-calibrated 3.6e-3; r4-r6 passed at <=1.95e-3).
//
// R6 post-mortem: k_attn at 9,430 cyc/CU-iter vs 512 MFMA-cyc/SIMD-iter —
// MfmaUtil 21% is a 4-SIMD sum; per-SIMD matrix occupancy 5%. 1 wave/SIMD
// (grid-limited: 65,536 q / 64 q-per-wave = 1,024 waves) exposes ALL
// intra-wave latency. R7: k'-SPLIT — 8 waves/block (512 thr), BK=128; waves
// 0-3 take k'-half 0, waves 4-7 half 1, same q-blocks. Per-wave work/iter
// unchanged, iters halve, waves/SIMD -> 2. Chipwide LDS/staging/MFMA bytes
// identical. Pair (w, w+4) partial O/l reduced through LDS (padded [64][132]
// f32 rows, barrier-fenced, same-type) at the end. Fixed-max softmax makes
// the split exact (l is a plain sum).
//
// ws layout (bytes):
//   xb   @ 0         : x   bf16 [4096][2048]   16777216
//   wqb  @ 16777216  : Wq  bf16 [2048][2048]    8388608
//   wkb  @ 25165824  : Wk  bf16 [128][2048]      524288
//   wvb  @ 25690112  : Wv  bf16 [128][2048]      524288
//   qb   @ 26214400  : Q   bf16 [4096][2048]   16777216  (pre-scaled log2e/sqrt(128))
//   kbuf @ 42991616  : K   bf16 [4096][128]     1048576
//   vtb  @ 44040192  : V^T bf16 [2][128][2048]  1048576
// total 45088768

typedef unsigned short u16;
typedef unsigned int u32;
typedef __bf16 bf16x8 __attribute__((ext_vector_type(8)));
typedef float f32x16 __attribute__((ext_vector_type(16)));
typedef u16 u16x4 __attribute__((ext_vector_type(4)));
typedef u32 u32x4 __attribute__((ext_vector_type(4)));

#define MFMA32(a, b, c) __builtin_amdgcn_mfma_f32_32x32x16_bf16((a), (b), (c), 0, 0, 0)

__device__ __forceinline__ u16 f2bf(float f) {
  __hip_bfloat16 h = __float2bfloat16(f);
  return __builtin_bit_cast(u16, h);
}

__device__ __forceinline__ float fexp2(float x) {
#if __has_builtin(__builtin_amdgcn_exp2f)
  return __builtin_amdgcn_exp2f(x);
#else
  return exp2f(x);
#endif
}

// async global->LDS, 16B per lane; LDS dest = wave-uniform base + lane*16
__device__ __forceinline__ void cp16(const void* g, void* l) {
  __builtin_amdgcn_global_load_lds(
      (const __attribute__((address_space(1))) u32*)g,
      (__attribute__((address_space(3))) u32*)l, 16, 0, 0);
}

__device__ __forceinline__ f32x16 zero16() {
  f32x16 v;
#pragma unroll
  for (int i = 0; i < 16; ++i) v[i] = 0.f;
  return v;
}

// ---------------------------------------------------------------- K1: convert
__global__ __launch_bounds__(256) void k_convert(
    const float* __restrict__ x, const float* __restrict__ wq,
    const float* __restrict__ wk, const float* __restrict__ wv,
    u16* __restrict__ xb, u16* __restrict__ wqb,
    u16* __restrict__ wkb, u16* __restrict__ wvb) {
  int idx = blockIdx.x * 256 + threadIdx.x;
  // float4 counts: x 2097152 | wq 1048576 | wk 65536 | wv 65536 = 3276800
  for (int i = idx; i < 3276800; i += 524288) {
    float4 v; u16* dst;
    if (i < 2097152) {
      v = ((const float4*)x)[i]; dst = xb + (size_t)i * 4;
    } else if (i < 3145728) {
      int j = i - 2097152; v = ((const float4*)wq)[j]; dst = wqb + (size_t)j * 4;
    } else if (i < 3211264) {
      int j = i - 3145728; v = ((const float4*)wk)[j]; dst = wkb + (size_t)j * 4;
    } else {
      int j = i - 3211264; v = ((const float4*)wv)[j]; dst = wvb + (size_t)j * 4;
    }
    u16x4 o;
    o[0] = f2bf(v.x); o[1] = f2bf(v.y); o[2] = f2bf(v.z); o[3] = f2bf(v.w);
    *(u16x4*)dst = o;
  }
}

// ------------------------------------------------- K2: Q and K/V^T projections
// grid (32, 18): y<16 -> Q col-blocks, y==16 -> K, y==17 -> V. 128x128 tile,
// BK=32. LDS: As[128][40] | Bs[128][40] (rows padded 32->40 u16; pad slots are
// included in the async-copy slot map so global_load_lds's contiguous lane*16
// layout matches the padded layout).
__global__ __launch_bounds__(256) void k_gemm_qkv(
    const u16* __restrict__ xb, const u16* __restrict__ wqb,
    const u16* __restrict__ wkb, const u16* __restrict__ wvb,
    const float* __restrict__ bq, const float* __restrict__ bk, const float* __restrict__ bv,
    u16* __restrict__ qout, u16* __restrict__ kout, u16* __restrict__ vtout) {
  __shared__ __align__(16) u16 sh[10240];
  const int tid = threadIdx.x;
  const int w = tid >> 6, lane = tid & 63, ln = lane & 31, hi = lane >> 5;
  const int wr = w >> 1, wc = w & 1;
  const int m0 = blockIdx.x * 128;
  const int by = blockIdx.y;
  const int mode = (by < 16) ? 0 : (by - 15);  // 0=Q, 1=K, 2=V (block-uniform)
  const int n0loc = (mode == 0) ? by * 128 : 0;
  const u16* __restrict__ Bp = (mode == 0) ? wqb : (mode == 1 ? wkb : wvb);
  const u16* Arow = xb + (size_t)m0 * 2048;
  const u16* Brow = Bp + (size_t)n0loc * 2048;

  // staging: 1280 slots of 16B (A 640 + B 640), 20 wave-slices, 5 per wave
  const u16* sb[5];
#pragma unroll
  for (int i = 0; i < 5; ++i) {
    int s = (w + i * 4) * 64 + lane;
    const u16* base; int r, c;
    if (s < 640) { r = s / 5; c = s % 5; if (c > 3) c = 0; base = Arow; }
    else { int s2 = s - 640; r = s2 / 5; c = s2 % 5; if (c > 3) c = 0; base = Brow; }
    sb[i] = base + (size_t)r * 2048 + c * 8;
  }

  f32x16 acc[2][2];
  acc[0][0] = zero16(); acc[0][1] = zero16(); acc[1][0] = zero16(); acc[1][1] = zero16();

  const int a0off = (wr * 64 + ln) * 40 + hi * 8;
  const int b0off = 5120 + (wc * 64 + ln) * 40 + hi * 8;

  for (int k0 = 0; k0 < 2048; k0 += 32) {
    __syncthreads();
#pragma unroll
    for (int i = 0; i < 5; ++i)
      cp16(sb[i] + k0, (void*)(sh + (w + i * 4) * 512));
    __syncthreads();
#pragma unroll
    for (int kc = 0; kc < 2; ++kc) {
      const int ko = kc * 16;
      bf16x8 a0 = *(const bf16x8*)&sh[a0off + ko];
      bf16x8 a1 = *(const bf16x8*)&sh[a0off + 1280 + ko];
      bf16x8 b0 = *(const bf16x8*)&sh[b0off + ko];
      bf16x8 b1 = *(const bf16x8*)&sh[b0off + 1280 + ko];
      acc[0][0] = MFMA32(a0, b0, acc[0][0]);
      acc[0][1] = MFMA32(a0, b1, acc[0][1]);
      acc[1][0] = MFMA32(a1, b0, acc[1][0]);
      acc[1][1] = MFMA32(a1, b1, acc[1][1]);
    }
  }

  // epilogue; C/D layout: col = lane&31, row = (r&3) + 8*(r>>2) + 4*(lane>>5)
  // qscale = log2(e)/sqrt(128): folds softmax scale + exp->exp2 into Q (exact).
  const float qscale = 0.12751744630098356f;
#pragma unroll
  for (int fm = 0; fm < 2; ++fm) {
#pragma unroll
    for (int fn = 0; fn < 2; ++fn) {
      f32x16 a = acc[fm][fn];
      const int mbase = m0 + wr * 64 + fm * 32;
      const int nloc = n0loc + wc * 64 + fn * 32 + ln;
      if (mode == 0) {
        const float bsc = bq[nloc] * qscale;
#pragma unroll
        for (int r = 0; r < 16; ++r) {
          int row = (r & 3) + 8 * (r >> 2) + 4 * hi;
          qout[(size_t)(mbase + row) * 2048 + nloc] = f2bf(a[r] * qscale + bsc);
        }
      } else if (mode == 1) {
        const float bb = bk[nloc];
#pragma unroll
        for (int r = 0; r < 16; ++r) {
          int row = (r & 3) + 8 * (r >> 2) + 4 * hi;
          kout[(size_t)(mbase + row) * 128 + nloc] = f2bf(a[r] + bb);
        }
      } else {
        const float bb = bv[nloc];
#pragma unroll
        for (int r = 0; r < 16; ++r) {
          int row = (r & 3) + 8 * (r >> 2) + 4 * hi;
          int m = mbase + row;
          vtout[(size_t)((m >> 11) * 128 + nloc) * 2048 + (m & 2047)] = f2bf(a[r] + bb);
        }
      }
    }
  }
}

// ------------------------------------------------------- K3: flash attention
// grid (8 qtiles, 16 heads, 2 batch), 512 thr = 8 waves, BQ=256, BK=128,
// k'-split: wave w handles q-block (w&3) x k'-half (w>>2). Double-buffered
// LDS, one barrier per iter. Fixed-max softmax, exp2 (log2e folded into Q).
// LDS per buffer: Ks[128][136] | Vts[128][136] u16 = 69,632 B; x2 = 139,264.
// End: pair (w, w+4) partial O/l reduced via LDS (f32 [64][132] rows, padded,
// barrier-fenced, same-type accesses).
__global__ __launch_bounds__(512, 2) void k_attn(
    const u16* __restrict__ qb, const u16* __restrict__ kb, const u16* __restrict__ vtb,
    float* __restrict__ out) {
  __shared__ __align__(16) u16 sh[69632];
  const int tid = threadIdx.x;
  const int w = tid >> 6, lane = tid & 63, ln = lane & 31, hi = lane >> 5;
  const int kh = w >> 2, qblk = w & 3;
  const int q0 = blockIdx.x * 256, h = blockIdx.y, b = blockIdx.z;
  const size_t bL = (size_t)b * 2048;
  const u16* kbase = kb + bL * 128;
  const u16* vbase = vtb + (size_t)b * 128 * 2048;

  // persistent Q fragments, 2 q-subblocks (B-op: col q = ln, k = kc*16+hi*8+j)
  bf16x8 qfA[8], qfB[8];
  {
    const u16* qrowA = qb + (bL + q0 + qblk * 64 + ln) * 2048 + h * 128 + hi * 8;
    const u16* qrowB = qrowA + 32 * 2048;
#pragma unroll
    for (int kc = 0; kc < 8; ++kc) {
      qfA[kc] = *(const bf16x8*)(qrowA + kc * 16);
      qfB[kc] = *(const bf16x8*)(qrowB + kc * 16);
    }
  }

  // staging: K 128 rows x 17 slots (16 data + 1 pad) = 2176 slots (slices
  // 0..33), V 128 d-rows x 17 = 2176 (slices 34..67). 68 slices over 8 waves.
  const u16* sb[9]; int smul[9];
  const int nsl = (w < 4) ? 9 : 8;
#pragma unroll
  for (int i = 0; i < 9; ++i) {
    int sl = w + i * 8;
    if (sl < 68) {
      int s = sl * 64 + lane;
      if (s < 2176) {
        int r = s / 17, c = s % 17; if (c > 15) c = 0;
        sb[i] = kbase + r * 128 + c * 8; smul[i] = 128;
      } else {
        int s2 = s - 2176; int d = s2 / 17, c = s2 % 17; if (c > 15) c = 0;
        sb[i] = vbase + (size_t)d * 2048 + c * 8; smul[i] = 1;
      }
    } else { sb[i] = kbase; smul[i] = 0; }
  }

  // prologue: stage tile 0 into buffer 0
#pragma unroll
  for (int i = 0; i < 9; ++i)
    if (i < nsl) cp16(sb[i], (void*)(sh + (w + i * 8) * 512));
  __syncthreads();

  f32x16 oA[4], oB[4];
#pragma unroll
  for (int dg = 0; dg < 4; ++dg) { oA[dg] = zero16(); oB[dg] = zero16(); }
  float lA = 0.f, lB = 0.f;

  // frag bases (u16 idx): Ks row = kh*64+ln; Vts at +17408, col = kh*64
  const int kro = (kh * 64 + ln) * 136 + hi * 8;
  const int vro = 17408 + ln * 136 + kh * 64 + hi * 8;

  for (int it = 0; it < 16; ++it) {
    const int cur = (it & 1) * 34816;
    const int nxt = 34816 - cur;
    // prefetch next BK=128 tile into idle buffer (last iter: refetch tile 0)
    const size_t k0n = (it < 15) ? (size_t)(it + 1) * 128 : 0;
#pragma unroll
    for (int i = 0; i < 9; ++i)
      if (i < nsl) cp16(sb[i] + k0n * smul[i], (void*)(sh + nxt + (w + i * 8) * 512));

    // S^T[k'][q] for this wave's 64 k' x 64 q (Q pre-scaled by log2e/sqrt(hd))
    f32x16 s0A = zero16(), s1A = zero16(), s0B = zero16(), s1B = zero16();
#pragma unroll
    for (int kc = 0; kc < 8; ++kc) {
      bf16x8 a0 = *(const bf16x8*)&sh[cur + kro + kc * 16];
      bf16x8 a1 = *(const bf16x8*)&sh[cur + kro + 4352 + kc * 16];
      s0A = MFMA32(a0, qfA[kc], s0A);
      s1A = MFMA32(a1, qfA[kc], s1A);
      s0B = MFMA32(a0, qfB[kc], s0B);
      s1B = MFMA32(a1, qfB[kc], s1B);
    }

    // p = exp2(s'), pack truncated-bf16 pairs via v_perm, sum l from the SAME
    // truncated values (ratio-consistent with PV).
    u32 pkA[16], pkB[16];
#pragma unroll
    for (int i = 0; i < 8; ++i) {
      float a = fexp2(s0A[2 * i]), c = fexp2(s0A[2 * i + 1]);
      pkA[i] = __builtin_amdgcn_perm(__builtin_bit_cast(u32, c),
                                     __builtin_bit_cast(u32, a), 0x07060302u);
      float d = fexp2(s1A[2 * i]), e = fexp2(s1A[2 * i + 1]);
      pkA[8 + i] = __builtin_amdgcn_perm(__builtin_bit_cast(u32, e),
                                         __builtin_bit_cast(u32, d), 0x07060302u);
      float f = fexp2(s0B[2 * i]), g = fexp2(s0B[2 * i + 1]);
      pkB[i] = __builtin_amdgcn_perm(__builtin_bit_cast(u32, g),
                                     __builtin_bit_cast(u32, f), 0x07060302u);
      float p = fexp2(s1B[2 * i]), q = fexp2(s1B[2 * i + 1]);
      pkB[8 + i] = __builtin_amdgcn_perm(__builtin_bit_cast(u32, q),
                                         __builtin_bit_cast(u32, p), 0x07060302u);
    }
#pragma unroll
    for (int i = 0; i < 16; ++i) {
      lA += __builtin_bit_cast(float, pkA[i] << 16);
      lA += __builtin_bit_cast(float, pkA[i] & 0xffff0000u);
      lB += __builtin_bit_cast(float, pkB[i] << 16);
      lB += __builtin_bit_cast(float, pkB[i] & 0xffff0000u);
    }

    // P^T B-frags: chunk c covers local k' = 16c + 8hi + j (r4-verified map).
    bf16x8 pfA[4], pfB[4];
#pragma unroll
    for (int c = 0; c < 4; ++c) {
      const int wb = 4 * c;
#pragma unroll
      for (int sel = 0; sel < 2; ++sel) {
        const u32* mat = sel ? pkB : pkA;
        u32 send0 = hi ? mat[wb] : mat[wb + 2];
        u32 send1 = hi ? mat[wb + 1] : mat[wb + 3];
        u32 r0 = (u32)__shfl_xor((int)send0, 32, 64);
        u32 r1 = (u32)__shfl_xor((int)send1, 32, 64);
        u32x4 v;
        v[0] = hi ? r0 : mat[wb];
        v[1] = hi ? r1 : mat[wb + 1];
        v[2] = hi ? mat[wb + 2] : r0;
        v[3] = hi ? mat[wb + 3] : r1;
        if (sel) pfB[c] = __builtin_bit_cast(bf16x8, v);
        else     pfA[c] = __builtin_bit_cast(bf16x8, v);
      }
    }

    // O^T += V^T(A) x P^T(B): V columns = this wave's k'-half (kh*64 + 16c)
#pragma unroll
    for (int c = 0; c < 4; ++c)
#pragma unroll
      for (int dg = 0; dg < 4; ++dg) {
        bf16x8 va = *(const bf16x8*)&sh[cur + vro + dg * 4352 + c * 16];
        oA[dg] = MFMA32(va, pfA[c], oA[dg]);
        oB[dg] = MFMA32(va, pfB[c], oB[dg]);
      }

    __syncthreads();  // drains own prefetch (vmcnt0) after compute; joins waves
  }

  // combine l across the two 32-k' register halves (lane ^ 32)
  lA += __shfl_xor(lA, 32, 64);
  lB += __shfl_xor(lB, 32, 64);

  // cross-wave (k'-half) reduction through LDS: upper waves write partials,
  // lower waves add + normalize + store. f32 rows padded to 132 (b128-clean).
  __syncthreads();  // all K/V reads done; LDS reusable
  float* shf = (float*)sh;
  float* lbuf = shf + 4 * 64 * 132;  // 4 x 8448 floats, then 256 l floats
  if (w >= 4) {
    float* op = shf + (w - 4) * (64 * 132);
#pragma unroll
    for (int dg = 0; dg < 4; ++dg)
#pragma unroll
      for (int rq = 0; rq < 4; ++rq) {
        const int d = dg * 32 + rq * 8 + hi * 4;
        float4 va, vb;
        va.x = oA[dg][rq * 4 + 0]; va.y = oA[dg][rq * 4 + 1];
        va.z = oA[dg][rq * 4 + 2]; va.w = oA[dg][rq * 4 + 3];
        vb.x = oB[dg][rq * 4 + 0]; vb.y = oB[dg][rq * 4 + 1];
        vb.z = oB[dg][rq * 4 + 2]; vb.w = oB[dg][rq * 4 + 3];
        *(float4*)&op[ln * 132 + d] = va;
        *(float4*)&op[(32 + ln) * 132 + d] = vb;
      }
    if (hi == 0) {
      lbuf[(w - 4) * 64 + ln] = lA;
      lbuf[(w - 4) * 64 + 32 + ln] = lB;
    }
  }
  __syncthreads();
  if (w < 4) {
    float* op = shf + w * (64 * 132);
    const float invA = 1.0f / (lA + lbuf[w * 64 + ln]);
    const float invB = 1.0f / (lB + lbuf[w * 64 + 32 + ln]);
    float* orowA = out + (bL + q0 + qblk * 64 + ln) * 2048 + h * 128 + hi * 4;
    float* orowB = orowA + 32 * 2048;
#pragma unroll
    for (int dg = 0; dg < 4; ++dg)
#pragma unroll
      for (int rq = 0; rq < 4; ++rq) {
        const int d = dg * 32 + rq * 8 + hi * 4;
        float4 pa = *(const float4*)&op[ln * 132 + d];
        float4 pb = *(const float4*)&op[(32 + ln) * 132 + d];
        float4 va, vb;
        va.x = (oA[dg][rq * 4 + 0] + pa.x) * invA;
        va.y = (oA[dg][rq * 4 + 1] + pa.y) * invA;
        va.z = (oA[dg][rq * 4 + 2] + pa.z) * invA;
        va.w = (oA[dg][rq * 4 + 3] + pa.w) * invA;
        vb.x = (oB[dg][rq * 4 + 0] + pb.x) * invB;
        vb.y = (oB[dg][rq * 4 + 1] + pb.y) * invB;
        vb.z = (oB[dg][rq * 4 + 2] + pb.z) * invB;
        vb.w = (oB[dg][rq * 4 + 3] + pb.w) * invB;
        *(float4*)&orowA[dg * 32 + rq * 8] = va;
        *(float4*)&orowB[dg * 32 + rq * 8] = vb;
      }
  }
}

// ----------------------------------------------------------------- launcher
extern "C" void kernel_launch(void* const* d_in, const int* in_sizes, int n_in,
                              void* d_out, int out_size, void* d_ws, size_t ws_size,
                              hipStream_t stream) {
  const float* x  = (const float*)d_in[0];
  const float* wq = (const float*)d_in[1];
  const float* bq = (const float*)d_in[2];
  const float* wk = (const float*)d_in[3];
  const float* bk = (const float*)d_in[4];
  const float* wv = (const float*)d_in[5];
  const float* bv = (const float*)d_in[6];
  float* out = (float*)d_out;
  char* ws = (char*)d_ws;

  u16* xb   = (u16*)(ws);
  u16* wqb  = (u16*)(ws + 16777216);
  u16* wkb  = (u16*)(ws + 25165824);
  u16* wvb  = (u16*)(ws + 25690112);
  u16* qb   = (u16*)(ws + 26214400);
  u16* kbuf = (u16*)(ws + 42991616);
  u16* vtb  = (u16*)(ws + 44040192);

  k_convert<<<2048, 256, 0, stream>>>(x, wq, wk, wv, xb, wqb, wkb, wvb);
  k_gemm_qkv<<<dim3(32, 18), 256, 0, stream>>>(xb, wqb, wkb, wvb, bq, bk, bv, qb, kbuf, vtb);
  k_attn<<<dim3(8, 16, 2), 512, 0, stream>>>(qb, kbuf, vtb, out);
}

// Round 8
// 354.089 us; speedup vs baseline: 1.0026x; 1.0026x over previous
//
#include <hip/hip_runtime.h>
#include <hip/hip_bf16.h>

// MQA fused pipeline, bf16 MFMA (32x32x16), fp32 accumulate.
// B=2, L=2048, D_MODEL=2048, H=16, HD=128.
// HARNESS DTYPES (established r1-r3): inputs fp32, OUTPUT fp32
// (threshold bf16-calibrated 3.6e-3; r4-r7 passed at <=1.95e-3).
//
// R7 post-mortem: k'-split achieved its occupancy goal (10.7 -> 21.7% = 2
// waves/SIMD) but __launch_bounds__(512,2) squeezed the allocator to 128
// VGPRs (per-wave state is ~320 regs) -> spill storm: FETCH 16.5->339 MB,
// WRITE 76->149 MB, 470 MB scratch traffic @2.7 TB/s = the whole 186 us.
// R8: __launch_bounds__(512,1) — budget up to ~512 unified regs/wave, no
// spill; 8-wave block still yields 2 waves/SIMD (2 x ~330 regs << 2048 pool).
// Everything else identical to r7 for clean attribution.
//
// ws layout (bytes):
//   xb   @ 0         : x   bf16 [4096][2048]   16777216
//   wqb  @ 16777216  : Wq  bf16 [2048][2048]    8388608
//   wkb  @ 25165824  : Wk  bf16 [128][2048]      524288
//   wvb  @ 25690112  : Wv  bf16 [128][2048]      524288
//   qb   @ 26214400  : Q   bf16 [4096][2048]   16777216  (pre-scaled log2e/sqrt(128))
//   kbuf @ 42991616  : K   bf16 [4096][128]     1048576
//   vtb  @ 44040192  : V^T bf16 [2][128][2048]  1048576
// total 45088768

typedef unsigned short u16;
typedef unsigned int u32;
typedef __bf16 bf16x8 __attribute__((ext_vector_type(8)));
typedef float f32x16 __attribute__((ext_vector_type(16)));
typedef u16 u16x4 __attribute__((ext_vector_type(4)));
typedef u32 u32x4 __attribute__((ext_vector_type(4)));

#define MFMA32(a, b, c) __builtin_amdgcn_mfma_f32_32x32x16_bf16((a), (b), (c), 0, 0, 0)

__device__ __forceinline__ u16 f2bf(float f) {
  __hip_bfloat16 h = __float2bfloat16(f);
  return __builtin_bit_cast(u16, h);
}

__device__ __forceinline__ float fexp2(float x) {
#if __has_builtin(__builtin_amdgcn_exp2f)
  return __builtin_amdgcn_exp2f(x);
#else
  return exp2f(x);
#endif
}

// async global->LDS, 16B per lane; LDS dest = wave-uniform base + lane*16
__device__ __forceinline__ void cp16(const void* g, void* l) {
  __builtin_amdgcn_global_load_lds(
      (const __attribute__((address_space(1))) u32*)g,
      (__attribute__((address_space(3))) u32*)l, 16, 0, 0);
}

__device__ __forceinline__ f32x16 zero16() {
  f32x16 v;
#pragma unroll
  for (int i = 0; i < 16; ++i) v[i] = 0.f;
  return v;
}

// ---------------------------------------------------------------- K1: convert
__global__ __launch_bounds__(256) void k_convert(
    const float* __restrict__ x, const float* __restrict__ wq,
    const float* __restrict__ wk, const float* __restrict__ wv,
    u16* __restrict__ xb, u16* __restrict__ wqb,
    u16* __restrict__ wkb, u16* __restrict__ wvb) {
  int idx = blockIdx.x * 256 + threadIdx.x;
  // float4 counts: x 2097152 | wq 1048576 | wk 65536 | wv 65536 = 3276800
  for (int i = idx; i < 3276800; i += 524288) {
    float4 v; u16* dst;
    if (i < 2097152) {
      v = ((const float4*)x)[i]; dst = xb + (size_t)i * 4;
    } else if (i < 3145728) {
      int j = i - 2097152; v = ((const float4*)wq)[j]; dst = wqb + (size_t)j * 4;
    } else if (i < 3211264) {
      int j = i - 3145728; v = ((const float4*)wk)[j]; dst = wkb + (size_t)j * 4;
    } else {
      int j = i - 3211264; v = ((const float4*)wv)[j]; dst = wvb + (size_t)j * 4;
    }
    u16x4 o;
    o[0] = f2bf(v.x); o[1] = f2bf(v.y); o[2] = f2bf(v.z); o[3] = f2bf(v.w);
    *(u16x4*)dst = o;
  }
}

// ------------------------------------------------- K2: Q and K/V^T projections
// grid (32, 18): y<16 -> Q col-blocks, y==16 -> K, y==17 -> V. 128x128 tile,
// BK=32. LDS: As[128][40] | Bs[128][40] (rows padded 32->40 u16; pad slots are
// included in the async-copy slot map so global_load_lds's contiguous lane*16
// layout matches the padded layout).
__global__ __launch_bounds__(256) void k_gemm_qkv(
    const u16* __restrict__ xb, const u16* __restrict__ wqb,
    const u16* __restrict__ wkb, const u16* __restrict__ wvb,
    const float* __restrict__ bq, const float* __restrict__ bk, const float* __restrict__ bv,
    u16* __restrict__ qout, u16* __restrict__ kout, u16* __restrict__ vtout) {
  __shared__ __align__(16) u16 sh[10240];
  const int tid = threadIdx.x;
  const int w = tid >> 6, lane = tid & 63, ln = lane & 31, hi = lane >> 5;
  const int wr = w >> 1, wc = w & 1;
  const int m0 = blockIdx.x * 128;
  const int by = blockIdx.y;
  const int mode = (by < 16) ? 0 : (by - 15);  // 0=Q, 1=K, 2=V (block-uniform)
  const int n0loc = (mode == 0) ? by * 128 : 0;
  const u16* __restrict__ Bp = (mode == 0) ? wqb : (mode == 1 ? wkb : wvb);
  const u16* Arow = xb + (size_t)m0 * 2048;
  const u16* Brow = Bp + (size_t)n0loc * 2048;

  // staging: 1280 slots of 16B (A 640 + B 640), 20 wave-slices, 5 per wave
  const u16* sb[5];
#pragma unroll
  for (int i = 0; i < 5; ++i) {
    int s = (w + i * 4) * 64 + lane;
    const u16* base; int r, c;
    if (s < 640) { r = s / 5; c = s % 5; if (c > 3) c = 0; base = Arow; }
    else { int s2 = s - 640; r = s2 / 5; c = s2 % 5; if (c > 3) c = 0; base = Brow; }
    sb[i] = base + (size_t)r * 2048 + c * 8;
  }

  f32x16 acc[2][2];
  acc[0][0] = zero16(); acc[0][1] = zero16(); acc[1][0] = zero16(); acc[1][1] = zero16();

  const int a0off = (wr * 64 + ln) * 40 + hi * 8;
  const int b0off = 5120 + (wc * 64 + ln) * 40 + hi * 8;

  for (int k0 = 0; k0 < 2048; k0 += 32) {
    __syncthreads();
#pragma unroll
    for (int i = 0; i < 5; ++i)
      cp16(sb[i] + k0, (void*)(sh + (w + i * 4) * 512));
    __syncthreads();
#pragma unroll
    for (int kc = 0; kc < 2; ++kc) {
      const int ko = kc * 16;
      bf16x8 a0 = *(const bf16x8*)&sh[a0off + ko];
      bf16x8 a1 = *(const bf16x8*)&sh[a0off + 1280 + ko];
      bf16x8 b0 = *(const bf16x8*)&sh[b0off + ko];
      bf16x8 b1 = *(const bf16x8*)&sh[b0off + 1280 + ko];
      acc[0][0] = MFMA32(a0, b0, acc[0][0]);
      acc[0][1] = MFMA32(a0, b1, acc[0][1]);
      acc[1][0] = MFMA32(a1, b0, acc[1][0]);
      acc[1][1] = MFMA32(a1, b1, acc[1][1]);
    }
  }

  // epilogue; C/D layout: col = lane&31, row = (r&3) + 8*(r>>2) + 4*(lane>>5)
  // qscale = log2(e)/sqrt(128): folds softmax scale + exp->exp2 into Q (exact).
  const float qscale = 0.12751744630098356f;
#pragma unroll
  for (int fm = 0; fm < 2; ++fm) {
#pragma unroll
    for (int fn = 0; fn < 2; ++fn) {
      f32x16 a = acc[fm][fn];
      const int mbase = m0 + wr * 64 + fm * 32;
      const int nloc = n0loc + wc * 64 + fn * 32 + ln;
      if (mode == 0) {
        const float bsc = bq[nloc] * qscale;
#pragma unroll
        for (int r = 0; r < 16; ++r) {
          int row = (r & 3) + 8 * (r >> 2) + 4 * hi;
          qout[(size_t)(mbase + row) * 2048 + nloc] = f2bf(a[r] * qscale + bsc);
        }
      } else if (mode == 1) {
        const float bb = bk[nloc];
#pragma unroll
        for (int r = 0; r < 16; ++r) {
          int row = (r & 3) + 8 * (r >> 2) + 4 * hi;
          kout[(size_t)(mbase + row) * 128 + nloc] = f2bf(a[r] + bb);
        }
      } else {
        const float bb = bv[nloc];
#pragma unroll
        for (int r = 0; r < 16; ++r) {
          int row = (r & 3) + 8 * (r >> 2) + 4 * hi;
          int m = mbase + row;
          vtout[(size_t)((m >> 11) * 128 + nloc) * 2048 + (m & 2047)] = f2bf(a[r] + bb);
        }
      }
    }
  }
}

// ------------------------------------------------------- K3: flash attention
// grid (8 qtiles, 16 heads, 2 batch), 512 thr = 8 waves, BQ=256, BK=128,
// k'-split: wave w handles q-block (w&3) x k'-half (w>>2). Double-buffered
// LDS, one barrier per iter. Fixed-max softmax, exp2 (log2e folded into Q).
// LDS per buffer: Ks[128][136] | Vts[128][136] u16 = 69,632 B; x2 = 139,264.
// End: pair (w, w+4) partial O/l reduced via LDS (f32 [64][132] rows, padded,
// barrier-fenced, same-type accesses).
// launch_bounds (512,1): r7's (512,2) capped VGPR at 128 -> spill storm
// (FETCH 339MB). (512,1) allows ~512 regs/wave; 2 waves/SIMD still fit.
__global__ __launch_bounds__(512, 1) void k_attn(
    const u16* __restrict__ qb, const u16* __restrict__ kb, const u16* __restrict__ vtb,
    float* __restrict__ out) {
  __shared__ __align__(16) u16 sh[69632];
  const int tid = threadIdx.x;
  const int w = tid >> 6, lane = tid & 63, ln = lane & 31, hi = lane >> 5;
  const int kh = w >> 2, qblk = w & 3;
  const int q0 = blockIdx.x * 256, h = blockIdx.y, b = blockIdx.z;
  const size_t bL = (size_t)b * 2048;
  const u16* kbase = kb + bL * 128;
  const u16* vbase = vtb + (size_t)b * 128 * 2048;

  // persistent Q fragments, 2 q-subblocks (B-op: col q = ln, k = kc*16+hi*8+j)
  bf16x8 qfA[8], qfB[8];
  {
    const u16* qrowA = qb + (bL + q0 + qblk * 64 + ln) * 2048 + h * 128 + hi * 8;
    const u16* qrowB = qrowA + 32 * 2048;
#pragma unroll
    for (int kc = 0; kc < 8; ++kc) {
      qfA[kc] = *(const bf16x8*)(qrowA + kc * 16);
      qfB[kc] = *(const bf16x8*)(qrowB + kc * 16);
    }
  }

  // staging: K 128 rows x 17 slots (16 data + 1 pad) = 2176 slots (slices
  // 0..33), V 128 d-rows x 17 = 2176 (slices 34..67). 68 slices over 8 waves.
  const u16* sb[9]; int smul[9];
  const int nsl = (w < 4) ? 9 : 8;
#pragma unroll
  for (int i = 0; i < 9; ++i) {
    int sl = w + i * 8;
    if (sl < 68) {
      int s = sl * 64 + lane;
      if (s < 2176) {
        int r = s / 17, c = s % 17; if (c > 15) c = 0;
        sb[i] = kbase + r * 128 + c * 8; smul[i] = 128;
      } else {
        int s2 = s - 2176; int d = s2 / 17, c = s2 % 17; if (c > 15) c = 0;
        sb[i] = vbase + (size_t)d * 2048 + c * 8; smul[i] = 1;
      }
    } else { sb[i] = kbase; smul[i] = 0; }
  }

  // prologue: stage tile 0 into buffer 0
#pragma unroll
  for (int i = 0; i < 9; ++i)
    if (i < nsl) cp16(sb[i], (void*)(sh + (w + i * 8) * 512));
  __syncthreads();

  f32x16 oA[4], oB[4];
#pragma unroll
  for (int dg = 0; dg < 4; ++dg) { oA[dg] = zero16(); oB[dg] = zero16(); }
  float lA = 0.f, lB = 0.f;

  // frag bases (u16 idx): Ks row = kh*64+ln; Vts at +17408, col = kh*64
  const int kro = (kh * 64 + ln) * 136 + hi * 8;
  const int vro = 17408 + ln * 136 + kh * 64 + hi * 8;

  for (int it = 0; it < 16; ++it) {
    const int cur = (it & 1) * 34816;
    const int nxt = 34816 - cur;
    // prefetch next BK=128 tile into idle buffer (last iter: refetch tile 0)
    const size_t k0n = (it < 15) ? (size_t)(it + 1) * 128 : 0;
#pragma unroll
    for (int i = 0; i < 9; ++i)
      if (i < nsl) cp16(sb[i] + k0n * smul[i], (void*)(sh + nxt + (w + i * 8) * 512));

    // S^T[k'][q] for this wave's 64 k' x 64 q (Q pre-scaled by log2e/sqrt(hd))
    f32x16 s0A = zero16(), s1A = zero16(), s0B = zero16(), s1B = zero16();
#pragma unroll
    for (int kc = 0; kc < 8; ++kc) {
      bf16x8 a0 = *(const bf16x8*)&sh[cur + kro + kc * 16];
      bf16x8 a1 = *(const bf16x8*)&sh[cur + kro + 4352 + kc * 16];
      s0A = MFMA32(a0, qfA[kc], s0A);
      s1A = MFMA32(a1, qfA[kc], s1A);
      s0B = MFMA32(a0, qfB[kc], s0B);
      s1B = MFMA32(a1, qfB[kc], s1B);
    }

    // p = exp2(s'), pack truncated-bf16 pairs via v_perm, sum l from the SAME
    // truncated values (ratio-consistent with PV).
    u32 pkA[16], pkB[16];
#pragma unroll
    for (int i = 0; i < 8; ++i) {
      float a = fexp2(s0A[2 * i]), c = fexp2(s0A[2 * i + 1]);
      pkA[i] = __builtin_amdgcn_perm(__builtin_bit_cast(u32, c),
                                     __builtin_bit_cast(u32, a), 0x07060302u);
      float d = fexp2(s1A[2 * i]), e = fexp2(s1A[2 * i + 1]);
      pkA[8 + i] = __builtin_amdgcn_perm(__builtin_bit_cast(u32, e),
                                         __builtin_bit_cast(u32, d), 0x07060302u);
      float f = fexp2(s0B[2 * i]), g = fexp2(s0B[2 * i + 1]);
      pkB[i] = __builtin_amdgcn_perm(__builtin_bit_cast(u32, g),
                                     __builtin_bit_cast(u32, f), 0x07060302u);
      float p = fexp2(s1B[2 * i]), q = fexp2(s1B[2 * i + 1]);
      pkB[8 + i] = __builtin_amdgcn_perm(__builtin_bit_cast(u32, q),
                                         __builtin_bit_cast(u32, p), 0x07060302u);
    }
#pragma unroll
    for (int i = 0; i < 16; ++i) {
      lA += __builtin_bit_cast(float, pkA[i] << 16);
      lA += __builtin_bit_cast(float, pkA[i] & 0xffff0000u);
      lB += __builtin_bit_cast(float, pkB[i] << 16);
      lB += __builtin_bit_cast(float, pkB[i] & 0xffff0000u);
    }

    // P^T B-frags: chunk c covers local k' = 16c + 8hi + j (r4-verified map).
    bf16x8 pfA[4], pfB[4];
#pragma unroll
    for (int c = 0; c < 4; ++c) {
      const int wb = 4 * c;
#pragma unroll
      for (int sel = 0; sel < 2; ++sel) {
        const u32* mat = sel ? pkB : pkA;
        u32 send0 = hi ? mat[wb] : mat[wb + 2];
        u32 send1 = hi ? mat[wb + 1] : mat[wb + 3];
        u32 r0 = (u32)__shfl_xor((int)send0, 32, 64);
        u32 r1 = (u32)__shfl_xor((int)send1, 32, 64);
        u32x4 v;
        v[0] = hi ? r0 : mat[wb];
        v[1] = hi ? r1 : mat[wb + 1];
        v[2] = hi ? mat[wb + 2] : r0;
        v[3] = hi ? mat[wb + 3] : r1;
        if (sel) pfB[c] = __builtin_bit_cast(bf16x8, v);
        else     pfA[c] = __builtin_bit_cast(bf16x8, v);
      }
    }

    // O^T += V^T(A) x P^T(B): V columns = this wave's k'-half (kh*64 + 16c)
#pragma unroll
    for (int c = 0; c < 4; ++c)
#pragma unroll
      for (int dg = 0; dg < 4; ++dg) {
        bf16x8 va = *(const bf16x8*)&sh[cur + vro + dg * 4352 + c * 16];
        oA[dg] = MFMA32(va, pfA[c], oA[dg]);
        oB[dg] = MFMA32(va, pfB[c], oB[dg]);
      }

    __syncthreads();  // drains own prefetch (vmcnt0) after compute; joins waves
  }

  // combine l across the two 32-k' register halves (lane ^ 32)
  lA += __shfl_xor(lA, 32, 64);
  lB += __shfl_xor(lB, 32, 64);

  // cross-wave (k'-half) reduction through LDS: upper waves write partials,
  // lower waves add + normalize + store. f32 rows padded to 132 (b128-clean).
  __syncthreads();  // all K/V reads done; LDS reusable
  float* shf = (float*)sh;
  float* lbuf = shf + 4 * 64 * 132;  // 4 x 8448 floats, then 256 l floats
  if (w >= 4) {
    float* op = shf + (w - 4) * (64 * 132);
#pragma unroll
    for (int dg = 0; dg < 4; ++dg)
#pragma unroll
      for (int rq = 0; rq < 4; ++rq) {
        const int d = dg * 32 + rq * 8 + hi * 4;
        float4 va, vb;
        va.x = oA[dg][rq * 4 + 0]; va.y = oA[dg][rq * 4 + 1];
        va.z = oA[dg][rq * 4 + 2]; va.w = oA[dg][rq * 4 + 3];
        vb.x = oB[dg][rq * 4 + 0]; vb.y = oB[dg][rq * 4 + 1];
        vb.z = oB[dg][rq * 4 + 2]; vb.w = oB[dg][rq * 4 + 3];
        *(float4*)&op[ln * 132 + d] = va;
        *(float4*)&op[(32 + ln) * 132 + d] = vb;
      }
    if (hi == 0) {
      lbuf[(w - 4) * 64 + ln] = lA;
      lbuf[(w - 4) * 64 + 32 + ln] = lB;
    }
  }
  __syncthreads();
  if (w < 4) {
    float* op = shf + w * (64 * 132);
    const float invA = 1.0f / (lA + lbuf[w * 64 + ln]);
    const float invB = 1.0f / (lB + lbuf[w * 64 + 32 + ln]);
    float* orowA = out + (bL + q0 + qblk * 64 + ln) * 2048 + h * 128 + hi * 4;
    float* orowB = orowA + 32 * 2048;
#pragma unroll
    for (int dg = 0; dg < 4; ++dg)
#pragma unroll
      for (int rq = 0; rq < 4; ++rq) {
        const int d = dg * 32 + rq * 8 + hi * 4;
        float4 pa = *(const float4*)&op[ln * 132 + d];
        float4 pb = *(const float4*)&op[(32 + ln) * 132 + d];
        float4 va, vb;
        va.x = (oA[dg][rq * 4 + 0] + pa.x) * invA;
        va.y = (oA[dg][rq * 4 + 1] + pa.y) * invA;
        va.z = (oA[dg][rq * 4 + 2] + pa.z) * invA;
        va.w = (oA[dg][rq * 4 + 3] + pa.w) * invA;
        vb.x = (oB[dg][rq * 4 + 0] + pb.x) * invB;
        vb.y = (oB[dg][rq * 4 + 1] + pb.y) * invB;
        vb.z = (oB[dg][rq * 4 + 2] + pb.z) * invB;
        vb.w = (oB[dg][rq * 4 + 3] + pb.w) * invB;
        *(float4*)&orowA[dg * 32 + rq * 8] = va;
        *(float4*)&orowB[dg * 32 + rq * 8] = vb;
      }
  }
}

// ----------------------------------------------------------------- launcher
extern "C" void kernel_launch(void* const* d_in, const int* in_sizes, int n_in,
                              void* d_out, int out_size, void* d_ws, size_t ws_size,
                              hipStream_t stream) {
  const float* x  = (const float*)d_in[0];
  const float* wq = (const float*)d_in[1];
  const float* bq = (const float*)d_in[2];
  const float* wk = (const float*)d_in[3];
  const float* bk = (const float*)d_in[4];
  const float* wv = (const float*)d_in[5];
  const float* bv = (const float*)d_in[6];
  float* out = (float*)d_out;
  char* ws = (char*)d_ws;

  u16* xb   = (u16*)(ws);
  u16* wqb  = (u16*)(ws + 16777216);
  u16* wkb  = (u16*)(ws + 25165824);
  u16* wvb  = (u16*)(ws + 25690112);
  u16* qb   = (u16*)(ws + 26214400);
  u16* kbuf = (u16*)(ws + 42991616);
  u16* vtb  = (u16*)(ws + 44040192);

  k_convert<<<2048, 256, 0, stream>>>(x, wq, wk, wv, xb, wqb, wkb, wvb);
  k_gemm_qkv<<<dim3(32, 18), 256, 0, stream>>>(xb, wqb, wkb, wvb, bq, bk, bv, qb, kbuf, vtb);
  k_attn<<<dim3(8, 16, 2), 512, 0, stream>>>(qb, kbuf, vtb, out);
}